// Round 10
// baseline (678.547 us; speedup 1.0000x reference)
//
#include <hip/hip_runtime.h>
#include <hip/hip_bf16.h>

// CrystalGraphConvNet fused pipeline for MI355X (gfx950).
// Inputs f32 (runtime-detected from gamma; bf16 path kept).
//
// u@w1 = x@W_a + x_gathered@W_n + nf@W_f. xay = x@[W_a|W_n] (one N=1024 GEMM);
// conv v6: z^T MFMA (operands swapped) -> f32 z tiles written to LDS with
// ds_write_b128 (no bf16 convert), epilogue reads float4 z; 2 tile-pairs of
// 256 cols; 1-shift/1-and bf16 unpack; GEMMs swizzled nt-fastest for A-tile
// L2 reuse; nf pre-converted to bf16 once; bn stats fused in h2 GEMM.

#define N_ATOM 20000
#define AF     256
#define F2     512
#define ORIG   92
#define ORIG_P 96
#define BB     200
#define KK     50
#define BN_EPS 1e-5f
#define ZSF    260      // sZf row stride in floats (256 + 4; keeps 16B align)

// canonical small-tensor block (bf16) element offsets
#define OFF_B1   0        // 3*512
#define OFF_B2   1536     // 3*256
#define OFF_GAM  2304     // 3*256
#define OFF_BET  3072     // 3*256
#define OFF_EMBB 3840     // 256
#define OFF_FCB  4096     // 256
#define OFF_FCW  4352     // 260*256
#define OFF_OW   70912    // 256
#define OFF_OB   71168    // 1
#define OFF_M2   71169    // 200*4
#define N_SMALL  71969

// prep_all segment sizes
#define S_AF   (N_ATOM * ORIG_P)
#define S_EMB  (AF * ORIG_P)
#define S_W12  (3 * 1024 * 256)
#define S_W1F  (3 * 512 * 64)
#define S_W2   (3 * AF * F2)
#define S_SM   N_SMALL
#define S_TOT  (S_AF + S_EMB + S_W12 + S_W1F + S_W2 + S_SM)

using bf16x8 = __attribute__((ext_vector_type(8))) short;
using f32x4  = __attribute__((ext_vector_type(4))) float;

__device__ __forceinline__ float bf2f(__hip_bfloat16 v) { return __bfloat162float(v); }
__device__ __forceinline__ __hip_bfloat16 f2bf(float v) { return __float2bfloat16(v); }
__device__ __forceinline__ unsigned short f2bfbits(float f) {   // RNE f32->bf16 bits
    unsigned u = __float_as_uint(f);
    u += 0x7fffu + ((u >> 16) & 1u);
    return (unsigned short)(u >> 16);
}
__device__ __forceinline__ float bflo(unsigned u) { return __uint_as_float(u << 16); }
__device__ __forceinline__ float bfhi(unsigned u) { return __uint_as_float(u & 0xffff0000u); }
__device__ __forceinline__ float softplus_f(float x) {
    return fmaxf(x, 0.f) + __logf(1.f + __expf(-fabsf(x)));
}
__device__ __forceinline__ float ld_any(const void* p, long idx, bool isf32) {
    return isf32 ? ((const float*)p)[idx] : bf2f(((const __hip_bfloat16*)p)[idx]);
}

// ---------------- dtype detect ----------------------------------------------
__global__ void detect_dtype(const unsigned* __restrict__ gamma_raw,
                             unsigned* __restrict__ flag) {
    unsigned u = gamma_raw[0];              // 1.0f = 0x3F800000 ; bf16 pair = 0x3F803F80
    flag[0] = ((u & 0xFFFFu) == 0u) ? 1u : 0u;
}

// ---------------- prep: nf -> canonical bf16 (once per launch) ---------------
__global__ __launch_bounds__(256) void prep_nf(const void* __restrict__ nf,
                                               const unsigned* __restrict__ dflag,
                                               unsigned* __restrict__ out) {
    bool isf32 = dflag[0] != 0u;
    int idx = blockIdx.x * 256 + threadIdx.x;        // one per 4 elems
    if (idx >= N_ATOM * 12 * 64 / 4) return;
    if (isf32) {
        float4 v = ((const float4*)nf)[idx];
        out[idx * 2]     = (unsigned)f2bfbits(v.x) | ((unsigned)f2bfbits(v.y) << 16);
        out[idx * 2 + 1] = (unsigned)f2bfbits(v.z) | ((unsigned)f2bfbits(v.w) << 16);
    } else {
        ((uint2*)out)[idx] = ((const uint2*)nf)[idx];
    }
}

// ---------------- merged prep ------------------------------------------------
__global__ __launch_bounds__(256)
void prep_all(const void* af, const void* emb_w, const void* w1, const void* w2,
              const void* b1, const void* b2, const void* gam, const void* bet,
              const void* embb, const void* fcb, const void* fcw,
              const void* ow, const void* ob, const void* m2,
              const unsigned* __restrict__ dflag,
              __hip_bfloat16* __restrict__ af_pad, __hip_bfloat16* __restrict__ embT,
              __hip_bfloat16* __restrict__ w1T2, __hip_bfloat16* __restrict__ w1Tf,
              __hip_bfloat16* __restrict__ w2T, __hip_bfloat16* __restrict__ smalls) {
    bool isf32 = dflag[0] != 0u;
    int i = blockIdx.x * 256 + threadIdx.x;
    if (i < S_AF) {
        int r = i / ORIG_P, k = i - r * ORIG_P;
        af_pad[i] = (k < ORIG) ? f2bf(ld_any(af, (long)r * ORIG + k, isf32)) : f2bf(0.f);
        return;
    }
    i -= S_AF;
    if (i < S_EMB) {
        int n = i / ORIG_P, k = i - n * ORIG_P;
        embT[i] = (k < ORIG) ? f2bf(ld_any(emb_w, (long)k * AF + n, isf32)) : f2bf(0.f);
        return;
    }
    i -= S_EMB;
    if (i < S_W12) {
        int l = i / (1024 * 256); int rem = i - l * (1024 * 256);
        int c = rem / 256, k = rem - c * 256;
        long src = (c < 512) ? ((long)(l * 576 + k) * F2 + c)
                             : ((long)(l * 576 + 256 + k) * F2 + (c - 512));
        w1T2[i] = f2bf(ld_any(w1, src, isf32));
        return;
    }
    i -= S_W12;
    if (i < S_W1F) {
        int l = i / (512 * 64); int rem = i - l * (512 * 64);
        int c = rem / 64, k = rem - c * 64;
        w1Tf[i] = f2bf(ld_any(w1, (long)(l * 576 + 512 + k) * F2 + c, isf32));
        return;
    }
    i -= S_W1F;
    if (i < S_W2) {
        int l = i / (AF * F2); int rem = i - l * (AF * F2);
        int n = rem / F2, k = rem - n * F2;
        w2T[i] = f2bf(ld_any(w2, (long)(l * F2 + k) * AF + n, isf32));
        return;
    }
    i -= S_W2;
    if (i >= S_SM) return;
    float v;
    if      (i < OFF_B2)   v = ld_any(b1,   i - OFF_B1,  isf32);
    else if (i < OFF_GAM)  v = ld_any(b2,   i - OFF_B2,  isf32);
    else if (i < OFF_BET)  v = ld_any(gam,  i - OFF_GAM, isf32);
    else if (i < OFF_EMBB) v = ld_any(bet,  i - OFF_BET, isf32);
    else if (i < OFF_FCB)  v = ld_any(embb, i - OFF_EMBB,isf32);
    else if (i < OFF_OW)   v = (i < OFF_FCW) ? ld_any(fcb, i - OFF_FCB, isf32)
                                             : ld_any(fcw, i - OFF_FCW, isf32);
    else if (i < OFF_OB)   v = ld_any(ow,   i - OFF_OW,  isf32);
    else if (i < OFF_M2)   v = ld_any(ob,   i - OFF_OB,  isf32);
    else                   v = ld_any(m2,   i - OFF_M2,  isf32);
    smalls[i] = f2bf(v);
}

// ---------------- generic MFMA GEMM: C = act(A @ B + bias) -------------------
// Grid = (n_tiles, m_tiles): nt = blockIdx.x (fastest) so consecutive blocks
// share the A row-tile (L2 temporal reuse).
template <bool OUT_BF16>
__global__ __launch_bounds__(256)
void gemm_kernel(const __hip_bfloat16* __restrict__ A, int lda,
                 const __hip_bfloat16* __restrict__ BT, int ldb,
                 void* __restrict__ Cp, int M, int ldc, int K,
                 const __hip_bfloat16* __restrict__ bias, int act,
                 float* __restrict__ st) {
    __shared__ __align__(16) unsigned short sA[128 * 40];
    __shared__ __align__(16) unsigned short sB[128 * 40];
    __shared__ float sS[128], sS2[128];
    int tid  = threadIdx.x;
    int nt   = blockIdx.x, mt = blockIdx.y;
    int wave = tid >> 6, lane = tid & 63, q = lane >> 4, ln = lane & 15;
    int wr   = wave >> 1, wc = wave & 1;

    if (st && tid < 128) { sS[tid] = 0.f; sS2[tid] = 0.f; }

    f32x4 acc[4][4];
    for (int i = 0; i < 4; i++)
        for (int j = 0; j < 4; j++) acc[i][j] = (f32x4){0.f, 0.f, 0.f, 0.f};

    for (int k0 = 0; k0 < K; k0 += 32) {
        for (int i = tid; i < 512; i += 256) {
            int r = i >> 2, ch = i & 3;
            int row = mt * 128 + r;
            uint4 va = make_uint4(0u, 0u, 0u, 0u);
            if (row < M) va = *(const uint4*)(A + (size_t)row * lda + k0 + ch * 8);
            *(uint4*)(&sA[r * 40 + ch * 8]) = va;
            int n = nt * 128 + r;
            uint4 vb = *(const uint4*)(BT + (size_t)n * ldb + k0 + ch * 8);
            *(uint4*)(&sB[r * 40 + ch * 8]) = vb;
        }
        __syncthreads();
        bf16x8 af[4], bf[4];
        for (int i = 0; i < 4; i++)
            af[i] = *(const bf16x8*)(&sA[(wr * 64 + i * 16 + ln) * 40 + q * 8]);
        for (int j = 0; j < 4; j++)
            bf[j] = *(const bf16x8*)(&sB[(wc * 64 + j * 16 + ln) * 40 + q * 8]);
        for (int i = 0; i < 4; i++)
            for (int j = 0; j < 4; j++)
                acc[i][j] = __builtin_amdgcn_mfma_f32_16x16x32_bf16(af[i], bf[j], acc[i][j], 0, 0, 0);
        __syncthreads();
    }
    for (int j = 0; j < 4; j++) {
        int cl  = wc * 64 + j * 16 + ln;
        int col = nt * 128 + cl;
        float bv = bias ? bf2f(bias[col]) : 0.f;
        float ls = 0.f, ls2 = 0.f;
        for (int i = 0; i < 4; i++) {
            for (int r = 0; r < 4; r++) {
                int row = mt * 128 + wr * 64 + i * 16 + q * 4 + r;
                if (row >= M) continue;
                float v = acc[i][j][r] + bv;
                if (st) { ls += v; ls2 += v * v; }
                if (act == 1) v = softplus_f(v);
                if (OUT_BF16) ((__hip_bfloat16*)Cp)[(size_t)row * ldc + col] = f2bf(v);
                else          ((float*)Cp)[(size_t)row * ldc + col] = v;
            }
        }
        if (st) { atomicAdd(&sS[cl], ls); atomicAdd(&sS2[cl], ls2); }
    }
    if (st) {
        __syncthreads();
        if (tid < 128) {
            int col = nt * 128 + tid;
            atomicAdd(&st[col], sS[tid]);
            atomicAdd(&st[AF + col], sS2[tid]);
        }
    }
}

// ---------------- fused conv v6 ---------------------------------------------
// 4 atoms/block. z^T MFMA: D cols = (atom,m) rows, lane regs = 4 consecutive
// weight cols -> ds_write_b128 f32 z (no convert). 2 passes of 256 cols.
// Epilogue: thread = (atom=wave, 4 cols), float4 z from LDS, coalesced y.
__global__ __launch_bounds__(256)
void conv_fused(const void* __restrict__ nf,              // [N][12][64]
                const unsigned* __restrict__ dflag,
                int prepped,                              // 1: nf canonical bf16
                const int* __restrict__ nidx,             // [N][12]
                const __hip_bfloat16* __restrict__ xay,   // [N][1024]: xa | y
                const __hip_bfloat16* __restrict__ b1l,   // [512]
                const __hip_bfloat16* __restrict__ w1TfL, // [512][64]
                __hip_bfloat16* __restrict__ ns)          // [N][512]
{
    __shared__ __align__(16) unsigned short sNF[48 * 72];  // 6.9 KB
    __shared__ __align__(16) float sZf[48 * ZSF];          // 49.9 KB
    __shared__ int sIdx[48];

    int tid = threadIdx.x;
    int ab  = blockIdx.x * 4;

    if (prepped || dflag[0] == 0u) {
        const __hip_bfloat16* nfB = (const __hip_bfloat16*)nf;
        for (int i = tid; i < 48 * 8; i += 256) {
            int r = i >> 3, ch = i & 7;
            uint4 v = *(const uint4*)(nfB + (size_t)(ab * 12 + r) * 64 + ch * 8);
            *(uint4*)(&sNF[r * 72 + ch * 8]) = v;
        }
    } else {
        const float* nfF = (const float*)nf;
        for (int i = tid; i < 48 * 8; i += 256) {
            int r = i >> 3, ch = i & 7;
            const float* src = nfF + (size_t)(ab * 12 + r) * 64 + ch * 8;
            float4 v0 = *(const float4*)(src);
            float4 v1 = *(const float4*)(src + 4);
            unsigned short* d = &sNF[r * 72 + ch * 8];
            d[0] = f2bfbits(v0.x); d[1] = f2bfbits(v0.y);
            d[2] = f2bfbits(v0.z); d[3] = f2bfbits(v0.w);
            d[4] = f2bfbits(v1.x); d[5] = f2bfbits(v1.y);
            d[6] = f2bfbits(v1.z); d[7] = f2bfbits(v1.w);
        }
    }
    if (tid < 48) sIdx[tid] = nidx[ab * 12 + tid];
    __syncthreads();

    int wave = tid >> 6, lane = tid & 63, q = lane >> 4, ln = lane & 15;
    int a = wave;                 // epilogue atom
    int n = ab + a;
    int gi[12];
#pragma unroll
    for (int m = 0; m < 12; m++) gi[m] = sIdx[a * 12 + m];

    for (int tp = 0; tp < 2; tp++) {
        int cbase = tp * 256;
        if (tp) __syncthreads();          // prev epilogue done reading sZf
        // ---- MFMA phase: wave covers weight-cols [wave*64, wave*64+64) ----
        int w0 = wave * 64;
        for (int wt = 0; wt < 4; wt++) {
            int wc = w0 + wt * 16;        // local wcol tile base (0..255)
            bf16x8 afr0 = *(const bf16x8*)(w1TfL + (size_t)(cbase + wc + ln) * 64 + q * 8);
            bf16x8 afr1 = *(const bf16x8*)(w1TfL + (size_t)(cbase + wc + ln) * 64 + 32 + q * 8);
            for (int rt = 0; rt < 3; rt++) {
                bf16x8 b0 = *(const bf16x8*)(&sNF[(rt * 16 + ln) * 72 + q * 8]);
                bf16x8 b1f = *(const bf16x8*)(&sNF[(rt * 16 + ln) * 72 + 32 + q * 8]);
                f32x4 acc = (f32x4){0.f, 0.f, 0.f, 0.f};
                acc = __builtin_amdgcn_mfma_f32_16x16x32_bf16(afr0, b0, acc, 0, 0, 0);
                acc = __builtin_amdgcn_mfma_f32_16x16x32_bf16(afr1, b1f, acc, 0, 0, 0);
                // lane holds z[(rt*16+ln)][wc + q*4 .. +3] (z^T D layout)
                *(f32x4*)(&sZf[(rt * 16 + ln) * ZSF + wc + q * 4]) = acc;
            }
        }
        __syncthreads();

        // ---- epilogue: thread owns (atom=wave, cols 4*lane..+3) ----
        int lc = lane * 4;
        int gc = cbase + lc;
        uint2 xau = *(const uint2*)(xay + (size_t)n * 1024 + gc);
        uint2 b1u = *(const uint2*)(b1l + gc);
        float xa0 = bflo(xau.x) + bflo(b1u.x);
        float xa1 = bfhi(xau.x) + bfhi(b1u.x);
        float xa2 = bflo(xau.y) + bflo(b1u.y);
        float xa3 = bfhi(xau.y) + bfhi(b1u.y);
        float r0 = 0.f, r1 = 0.f, r2 = 0.f, r3 = 0.f;
#pragma unroll
        for (int m = 0; m < 12; m++) {
            float4 z = *(const float4*)(&sZf[(a * 12 + m) * ZSF + lc]);
            uint2 yy = *(const uint2*)(xay + (size_t)gi[m] * 1024 + 512 + gc);
            float v0 = z.x + xa0 + bflo(yy.x);
            float v1 = z.y + xa1 + bfhi(yy.x);
            float v2 = z.z + xa2 + bflo(yy.y);
            float v3 = z.w + xa3 + bfhi(yy.y);
            if (m < 6) {
                v0 = fmaxf(v0, 0.f); v1 = fmaxf(v1, 0.f);
                v2 = fmaxf(v2, 0.f); v3 = fmaxf(v3, 0.f);
            } else {
                v0 = softplus_f(v0); v1 = softplus_f(v1);
                v2 = softplus_f(v2); v3 = softplus_f(v3);
            }
            r0 += v0; r1 += v1; r2 += v2; r3 += v3;
        }
        uint2 o;
        o.x = (unsigned)f2bfbits(r0) | ((unsigned)f2bfbits(r1) << 16);
        o.y = (unsigned)f2bfbits(r2) | ((unsigned)f2bfbits(r3) << 16);
        *(uint2*)(ns + (size_t)n * F2 + gc) = o;
    }
}

// ---------------- batchnorm apply (stats fused into h2 GEMM) -----------------
__global__ __launch_bounds__(256)
void bn_apply(const __hip_bfloat16* __restrict__ h2, const float* __restrict__ st,
              const __hip_bfloat16* __restrict__ x,
              const __hip_bfloat16* __restrict__ gamma,
              const __hip_bfloat16* __restrict__ beta,
              __hip_bfloat16* __restrict__ xo) {
    int i = (blockIdx.x * 256 + threadIdx.x) * 8;
    int c = i & 255;
    uint4 hv = *(const uint4*)(h2 + i);
    uint4 xv = *(const uint4*)(x + i);
    unsigned hw[4] = {hv.x, hv.y, hv.z, hv.w};
    unsigned xw[4] = {xv.x, xv.y, xv.z, xv.w};
    unsigned ow[4];
    float r[8];
#pragma unroll
    for (int k = 0; k < 8; k++) {
        int cc = c + k;
        float mu  = st[cc] * (1.f / 20000.f);
        float var = fmaxf(st[AF + cc] * (1.f / 20000.f) - mu * mu, 0.f);
        unsigned hh = hw[k >> 1], xx = xw[k >> 1];
        float h  = (k & 1) ? bfhi(hh) : bflo(hh);
        float xf = (k & 1) ? bfhi(xx) : bflo(xx);
        float t = (h - mu) * rsqrtf(var + BN_EPS) * bf2f(gamma[cc]) + bf2f(beta[cc]);
        r[k] = softplus_f(xf + t);
    }
#pragma unroll
    for (int k = 0; k < 4; k++)
        ow[k] = (unsigned)f2bfbits(r[2 * k]) | ((unsigned)f2bfbits(r[2 * k + 1]) << 16);
    *(uint4*)(xo + i) = make_uint4(ow[0], ow[1], ow[2], ow[3]);
}

// ---------------- readout: segment mean + 2-layer MLP ------------------------
__global__ __launch_bounds__(256)
void readout(const __hip_bfloat16* __restrict__ x, const int* __restrict__ m1,
             const __hip_bfloat16* __restrict__ smalls,
             const unsigned* __restrict__ dflag,
             void* __restrict__ outp) {
    __shared__ float sc[AF + 4];
    __shared__ float sred[4];
    bool isf32 = dflag[0] != 0u;
    int b = blockIdx.x, tid = threadIdx.x;
    float s = 0.f;
    for (int j = 0; j < KK; j++) {
        int row = m1[b * KK + j];
        s += bf2f(x[(size_t)row * AF + tid]);
    }
    sc[tid] = softplus_f(s * (1.f / (float)KK));
    if (tid < 4) sc[AF + tid] = softplus_f(bf2f(smalls[OFF_M2 + b * 4 + tid]));
    __syncthreads();
    float acc = bf2f(smalls[OFF_FCB + tid]);
    for (int k = 0; k < AF + 4; k++) acc += sc[k] * bf2f(smalls[OFF_FCW + k * 256 + tid]);
    float h = softplus_f(acc);
    float v = h * bf2f(smalls[OFF_OW + tid]);
    for (int off = 32; off > 0; off >>= 1) v += __shfl_down(v, off);
    if ((tid & 63) == 0) sred[tid >> 6] = v;
    __syncthreads();
    if (tid == 0) {
        float o = sred[0] + sred[1] + sred[2] + sred[3] + bf2f(smalls[OFF_OB]);
        if (isf32) ((float*)outp)[b] = o;
        else       ((__hip_bfloat16*)outp)[b] = f2bf(o);
    }
}

// ---------------- host ------------------------------------------------------
extern "C" void kernel_launch(void* const* d_in, const int* in_sizes, int n_in,
                              void* d_out, int out_size, void* d_ws, size_t ws_size,
                              hipStream_t stream) {
    const void* atom_fea = d_in[0];
    const void* nbr_fea  = d_in[1];
    const int*  nbr_idx  = (const int*)d_in[2];
    const int*  m1_idx   = (const int*)d_in[3];
    /* d_in[4] seg_ids: unused */
    const void* m2_fea = d_in[5];
    const void* emb_w  = d_in[6];
    const void* emb_b  = d_in[7];
    const void* w1     = d_in[8];
    const void* b1     = d_in[9];
    const void* w2     = d_in[10];
    const void* b2     = d_in[11];
    const void* gamma  = d_in[12];
    const void* beta   = d_in[13];
    const void* fc_w   = d_in[14];
    const void* fc_b   = d_in[15];
    const void* out_w  = d_in[16];
    const void* out_b  = d_in[17];

    // ---- aliased workspace (~85 MB core + 30.7 MB optional nfb) ----
    char* ws = (char*)d_ws;
    size_t off = 0;
    auto alloc = [&](size_t bytes) -> char* {
        char* p = ws + off;
        off += (bytes + 255) & ~(size_t)255;
        return p;
    };
    __hip_bfloat16* w1T2   = (__hip_bfloat16*)alloc((size_t)S_W12 * 2);
    __hip_bfloat16* w1Tf   = (__hip_bfloat16*)alloc((size_t)S_W1F * 2);
    __hip_bfloat16* w2T    = (__hip_bfloat16*)alloc((size_t)S_W2 * 2);
    __hip_bfloat16* smalls = (__hip_bfloat16*)alloc((size_t)N_SMALL * 2);
    __hip_bfloat16* xb0    = (__hip_bfloat16*)alloc((size_t)N_ATOM * AF * 2);
    __hip_bfloat16* xb1    = (__hip_bfloat16*)alloc((size_t)N_ATOM * AF * 2);
    char*           regXY  = alloc((size_t)N_ATOM * 1024 * 2);
    char*           regZ   = alloc((size_t)N_ATOM * F2 * 2);
    float*          stats  = (float*)alloc((size_t)3 * 2 * AF * 4);
    unsigned*       dflag  = (unsigned*)alloc(256);
    char*           nfb    = alloc((size_t)N_ATOM * 12 * 64 * 2);   // 30.72 MB
    int use_nfb = (ws_size >= off) ? 1 : 0;

    __hip_bfloat16* xay    = (__hip_bfloat16*)regXY;
    __hip_bfloat16* h2     = (__hip_bfloat16*)regXY;
    __hip_bfloat16* af_pad = (__hip_bfloat16*)(regXY + (size_t)N_ATOM * F2 * 2);
    __hip_bfloat16* embT   = (__hip_bfloat16*)regZ;
    __hip_bfloat16* nsb    = (__hip_bfloat16*)regZ;

    detect_dtype<<<1, 1, 0, stream>>>((const unsigned*)gamma, dflag);
    (void)hipMemsetAsync(stats, 0, (size_t)3 * 2 * AF * 4, stream);

    if (use_nfb)
        prep_nf<<<(N_ATOM * 12 * 64 / 4 + 255) / 256, 256, 0, stream>>>(nbr_fea, dflag,
                                                                        (unsigned*)nfb);
    prep_all<<<(S_TOT + 255) / 256, 256, 0, stream>>>(
        atom_fea, emb_w, w1, w2, b1, b2, gamma, beta, emb_b, fc_b, fc_w,
        out_w, out_b, m2_fea, dflag, af_pad, embT, w1T2, w1Tf, w2T, smalls);

    // embed: x = softplus(af_pad @ emb_w + emb_b)   grid = (n_tiles, m_tiles)
    dim3 g_emb(2, (N_ATOM + 127) / 128);
    gemm_kernel<true><<<g_emb, 256, 0, stream>>>(af_pad, ORIG_P, embT, ORIG_P,
                                                 xb0, N_ATOM, AF, ORIG_P,
                                                 smalls + OFF_EMBB, 1, nullptr);

    const void* nf_conv = use_nfb ? (const void*)nfb : nbr_fea;

    __hip_bfloat16* xc = xb0;
    __hip_bfloat16* xn = xb1;
    for (int l = 0; l < 3; l++) {
        dim3 gxy(8, (N_ATOM + 127) / 128);
        gemm_kernel<true><<<gxy, 256, 0, stream>>>(xc, AF, w1T2 + (size_t)l * 1024 * 256, 256,
                                                   xay, N_ATOM, 1024, AF, nullptr, 0, nullptr);
        conv_fused<<<N_ATOM / 4, 256, 0, stream>>>(nf_conv, dflag, use_nfb, nbr_idx, xay,
                                                   smalls + OFF_B1 + l * F2,
                                                   w1Tf + (size_t)l * 512 * 64, nsb);
        float* stl = stats + l * 2 * AF;
        dim3 gh2(2, (N_ATOM + 127) / 128);
        gemm_kernel<true><<<gh2, 256, 0, stream>>>(nsb, F2, w2T + (size_t)l * AF * F2, F2,
                                                   h2, N_ATOM, AF, F2,
                                                   smalls + OFF_B2 + l * AF, 0, stl);
        bn_apply<<<(N_ATOM * AF / 8) / 256, 256, 0, stream>>>(h2, stl, xc,
                                                              smalls + OFF_GAM + l * AF,
                                                              smalls + OFF_BET + l * AF, xn);
        __hip_bfloat16* t = xc; xc = xn; xn = t;
    }
    readout<<<BB, 256, 0, stream>>>(xc, m1_idx, smalls, dflag, d_out);
}